// Round 1
// baseline (649.628 us; speedup 1.0000x reference)
//
#include <hip/hip_runtime.h>
#include <math.h>

namespace {

constexpr int B_ = 16;
constexpr int H_ = 512;
constexpr int W_ = 512;
constexpr int HW_ = H_ * W_;
constexpr int TS_ = 32;
constexpr int CAP_ = 4096;   // max candidates kept per image (>= 64*64 block maxima)
constexpr int NSEL_ = 500;

// 7-tap gaussian, sigma=1, normalized (matches reference's np.exp/ sum)
__device__ __constant__ float c_gw[7] = {
    0.004433048175243746f, 0.05400558262251428f, 0.24203622937611957f,
    0.3990502796522496f,  0.24203622937611957f, 0.05400558262251428f,
    0.004433048175243746f};

__device__ inline int reflect_i(int i, int n) {
  // jnp.pad mode='reflect': -1 -> 1, n -> n-2
  return i < 0 ? -i : (i > n - 1 ? 2 * (n - 1) - i : i);
}

// K1: imgs -> GFTT response map. One block = one 32x32 output tile.
// gray halo 4 (blur r=3 + sobel r=1), products halo 3 (reflect-padded),
// vertical blur into v_s, horizontal blur + response to global.
__global__ __launch_bounds__(256) void k_resp(const float* __restrict__ imgs,
                                              float* __restrict__ resp) {
  int bid = blockIdx.x;
  int bx = bid & 15, by = (bid >> 4) & 15, b = bid >> 8;
  int r0 = by * TS_, c0 = bx * TS_;
  __shared__ float g_s[40][40];
  __shared__ float p_s[3][38][38];
  __shared__ float v_s[3][TS_][38];
  int tid = threadIdx.x;
  const float* img = imgs + (size_t)b * 3 * HW_;

  // grayscale with replicate clamp (matches sobel's edge padding)
  for (int l = tid; l < 40 * 40; l += 256) {
    int lr = l / 40, lc = l % 40;
    int gr = min(max(r0 - 4 + lr, 0), H_ - 1);
    int gc = min(max(c0 - 4 + lc, 0), W_ - 1);
    int o = gr * W_ + gc;
    g_s[lr][lc] = 0.299f * img[o] + 0.587f * img[HW_ + o] + 0.114f * img[2 * HW_ + o];
  }
  __syncthreads();

  // gradient products at rows/cols tile-3 .. tile+34, reflect-mapped into image
  for (int l = tid; l < 38 * 38; l += 256) {
    int lr = l / 38, lc = l % 38;
    int ar = reflect_i(r0 - 3 + lr, H_);
    int ac = reflect_i(c0 - 3 + lc, W_);
    int rm = max(ar - 1, 0)      - (r0 - 4);
    int rz = ar                  - (r0 - 4);
    int rp = min(ar + 1, H_ - 1) - (r0 - 4);
    int cm = max(ac - 1, 0)      - (c0 - 4);
    int cz = ac                  - (c0 - 4);
    int cp = min(ac + 1, W_ - 1) - (c0 - 4);
    float gnw = g_s[rm][cm], gn = g_s[rm][cz], gne = g_s[rm][cp];
    float gw_ = g_s[rz][cm],                   ge  = g_s[rz][cp];
    float gsw = g_s[rp][cm], gs = g_s[rp][cz], gse = g_s[rp][cp];
    float dx = ((gne - gnw) + 2.f * (ge - gw_) + (gse - gsw)) * 0.125f;
    float dy = ((gsw - gnw) + 2.f * (gs - gn) + (gse - gne)) * 0.125f;
    p_s[0][lr][lc] = dx * dx;
    p_s[1][lr][lc] = dy * dy;
    p_s[2][lr][lc] = dx * dy;
  }
  __syncthreads();

  // vertical 7-tap blur: rows tile+0..31, cols tile-3..tile+34
  for (int l = tid; l < TS_ * 38; l += 256) {
    int lr = l / 38, lc = l % 38;
    float s0 = 0.f, s1 = 0.f, s2 = 0.f;
#pragma unroll
    for (int k = 0; k < 7; k++) {
      float w = c_gw[k];
      s0 += w * p_s[0][lr + k][lc];
      s1 += w * p_s[1][lr + k][lc];
      s2 += w * p_s[2][lr + k][lc];
    }
    v_s[0][lr][lc] = s0;
    v_s[1][lr][lc] = s1;
    v_s[2][lr][lc] = s2;
  }
  __syncthreads();

  // horizontal blur + min-eigenvalue response
  for (int l = tid; l < TS_ * TS_; l += 256) {
    int lr = l / TS_, lc = l % TS_;
    float b0 = 0.f, b1 = 0.f, b2 = 0.f;
#pragma unroll
    for (int k = 0; k < 7; k++) {
      float w = c_gw[k];
      b0 += w * v_s[0][lr][lc + k];
      b1 += w * v_s[1][lr][lc + k];
      b2 += w * v_s[2][lr][lc + k];
    }
    float tr = b0 + b1;
    float det = b0 * b1 - b2 * b2;
    float r = 0.5f * (tr - sqrtf(fabsf(tr * tr - 4.f * det) + 1e-12f));
    resp[((size_t)b * H_ + (r0 + lr)) * W_ + (c0 + lc)] = r;
  }
}

// K2: 5x5 NMS (pad=-inf) + per-8x8-block max; append positive block-maxima
// as (value, flat_idx) candidates.
__global__ __launch_bounds__(256) void k_nms(const float* __restrict__ resp,
                                             float* __restrict__ cand_val,
                                             int* __restrict__ cand_idx,
                                             int* __restrict__ cand_cnt) {
  int bid = blockIdx.x;
  int bx = bid & 15, by = (bid >> 4) & 15, b = bid >> 8;
  int r0 = by * TS_, c0 = bx * TS_;
  __shared__ float r_s[36][36];
  __shared__ float c_s[32][32];
  __shared__ float pm[16][17];
  int tid = threadIdx.x;
  const float* rb = resp + (size_t)b * HW_;
  for (int l = tid; l < 36 * 36; l += 256) {
    int lr = l / 36, lc = l % 36;
    int gr = r0 - 2 + lr, gc = c0 - 2 + lc;
    float v = -INFINITY;
    if (gr >= 0 && gr < H_ && gc >= 0 && gc < W_) v = rb[gr * W_ + gc];
    r_s[lr][lc] = v;
  }
  __syncthreads();
  for (int l = tid; l < 1024; l += 256) {
    int lr = l >> 5, lc = l & 31;
    float v = r_s[lr + 2][lc + 2];
    float m = -INFINITY;
#pragma unroll
    for (int u = 0; u < 5; u++)
#pragma unroll
      for (int w = 0; w < 5; w++) m = fmaxf(m, r_s[lr + u][lc + w]);
    c_s[lr][lc] = (v == m) ? v : 0.f;
  }
  __syncthreads();
  // 8x8 block max: 16 sub-blocks x 16 threads, 4 cells each
  {
    int sub = tid >> 4, k = tid & 15;
    int sr = (sub >> 2) << 3, sc = (sub & 3) << 3;
    float m = -INFINITY;
#pragma unroll
    for (int c = 0; c < 4; c++) {
      int cell = k * 4 + c;
      m = fmaxf(m, c_s[sr + (cell >> 3)][sc + (cell & 7)]);
    }
    pm[sub][k] = m;
  }
  __syncthreads();
  if (tid < 16) {
    float m = -INFINITY;
    for (int k = 0; k < 16; k++) m = fmaxf(m, pm[tid][k]);
    pm[tid][16] = m;
  }
  __syncthreads();
  for (int l = tid; l < 1024; l += 256) {
    int lr = l >> 5, lc = l & 31;
    float v = c_s[lr][lc];
    int sub = ((lr >> 3) << 2) | (lc >> 3);
    if (v > 0.f && v == pm[sub][16]) {
      int pos = atomicAdd(&cand_cnt[b], 1);
      if (pos < CAP_) {
        cand_val[b * CAP_ + pos] = v;
        cand_idx[b * CAP_ + pos] = (r0 + lr) * W_ + (c0 + lc);
      }
    }
  }
}

// K3: per-image top-500 via in-LDS bitonic sort, order (value desc, idx asc)
// to match jax.lax.top_k tie-breaking.
__global__ __launch_bounds__(1024) void k_topk(const float* __restrict__ cand_val,
                                               const int* __restrict__ cand_idx,
                                               const int* __restrict__ cand_cnt,
                                               float* __restrict__ sel_val,
                                               int* __restrict__ sel_idx,
                                               int* __restrict__ sel_cnt) {
  int b = blockIdx.x;
  __shared__ float v_s[CAP_];
  __shared__ int i_s[CAP_];
  int tid = threadIdx.x;
  int n = min(cand_cnt[b], CAP_);
  for (int l = tid; l < CAP_; l += 1024) {
    if (l < n) {
      v_s[l] = cand_val[b * CAP_ + l];
      i_s[l] = cand_idx[b * CAP_ + l];
    } else {
      v_s[l] = -INFINITY;
      i_s[l] = 0x7FFFFFFF;
    }
  }
  __syncthreads();
  for (int k = 2; k <= CAP_; k <<= 1) {
    for (int j = k >> 1; j > 0; j >>= 1) {
      for (int t = tid; t < CAP_ / 2; t += 1024) {
        int i = ((t & ~(j - 1)) << 1) | (t & (j - 1));
        int ixj = i | j;
        bool up = ((i & k) == 0);
        float va = v_s[i], vb = v_s[ixj];
        int ia = i_s[i], ib = i_s[ixj];
        bool b_first = (vb > va) || (vb == va && ib < ia);  // strict: b ranks before a
        bool a_first = (va > vb) || (va == vb && ia < ib);
        bool sw = up ? b_first : a_first;
        if (sw) {
          v_s[i] = vb; v_s[ixj] = va;
          i_s[i] = ib; i_s[ixj] = ia;
        }
      }
      __syncthreads();
    }
  }
  int m = min(n, NSEL_);
  if (tid < m) {
    sel_val[b * 512 + tid] = v_s[tid];
    sel_idx[b * 512 + tid] = i_s[tid];
  }
  if (tid == 0) sel_cnt[b] = m;
}

// K4: second 5x5 NMS on the sparse selected set (pairwise, strict-greater
// suppresses; equal survives, matching x==maxpool) + corner BCE terms.
__global__ __launch_bounds__(512) void k_corner(const float* __restrict__ sel_val,
                                                const int* __restrict__ sel_idx,
                                                const int* __restrict__ sel_cnt,
                                                const float* __restrict__ scores,
                                                double* __restrict__ acc) {
  int b = blockIdx.x;
  __shared__ float v_s[512];
  __shared__ int h_s[512], w_s[512];
  __shared__ float wsum[8];
  int tid = threadIdx.x;
  int m = sel_cnt[b];
  if (tid < m) {
    v_s[tid] = sel_val[b * 512 + tid];
    int idx = sel_idx[b * 512 + tid];
    h_s[tid] = idx >> 9;
    w_s[tid] = idx & 511;
  }
  __syncthreads();
  float term = 0.f;
  if (tid < m) {
    float v = v_s[tid];
    int h = h_s[tid], w = w_s[tid];
    bool keep = true;
    for (int j = 0; j < m; j++) {
      if (j == tid) continue;
      int dh = h - h_s[j], dw = w - w_s[j];
      if (dh >= -2 && dh <= 2 && dw >= -2 && dw <= 2 && v_s[j] > v) {
        keep = false;
        break;
      }
    }
    if (keep) {
      float p = scores[(size_t)b * HW_ + h * W_ + w];
      float lp = fmaxf(logf(p), -100.f);
      float l1p = fmaxf(log1pf(-p), -100.f);
      term = lp - l1p;  // corner pixel swaps log1p(-p) term for log(p)
    }
  }
  for (int off = 32; off > 0; off >>= 1) term += __shfl_down(term, off);
  if ((tid & 63) == 0) wsum[tid >> 6] = term;
  __syncthreads();
  if (tid == 0) {
    double s = 0.0;
    for (int i = 0; i < 8; i++) s += (double)wsum[i];
    atomicAdd(acc, s);
  }
}

// K5: sum of clamp(log1p(-p), -100) over all pixels.
__global__ __launch_bounds__(256) void k_base(const float* __restrict__ scores,
                                              double* __restrict__ acc) {
  __shared__ float wsum[4];
  int tid = threadIdx.x;
  size_t gid = (size_t)blockIdx.x * 256 + tid;
  size_t stride = (size_t)gridDim.x * 256;
  float s = 0.f;
  const float4* s4 = (const float4*)scores;
  size_t n4 = (size_t)B_ * HW_ / 4;
  for (size_t i = gid; i < n4; i += stride) {
    float4 p = s4[i];
    s += fmaxf(log1pf(-p.x), -100.f);
    s += fmaxf(log1pf(-p.y), -100.f);
    s += fmaxf(log1pf(-p.z), -100.f);
    s += fmaxf(log1pf(-p.w), -100.f);
  }
  for (int off = 32; off > 0; off >>= 1) s += __shfl_down(s, off);
  if ((tid & 63) == 0) wsum[tid >> 6] = s;
  __syncthreads();
  if (tid == 0) {
    double t = 0.0;
    for (int i = 0; i < 4; i++) t += (double)wsum[i];
    atomicAdd(acc, t);
  }
}

__global__ void k_final(const double* __restrict__ acc, float* __restrict__ out) {
  out[0] = (float)(-acc[0] / (double)((size_t)B_ * HW_));
}

}  // namespace

extern "C" void kernel_launch(void* const* d_in, const int* in_sizes, int n_in,
                              void* d_out, int out_size, void* d_ws, size_t ws_size,
                              hipStream_t stream) {
  const float* scores = (const float*)d_in[0];
  const float* imgs = (const float*)d_in[1];
  float* out = (float*)d_out;

  char* ws = (char*)d_ws;
  double* acc = (double*)ws;                       // 8 B
  int* cand_cnt = (int*)(ws + 8);                  // 16 ints
  int* sel_cnt = (int*)(ws + 72);                  // 16 ints
  float* resp = (float*)(ws + 256);                // 16 MB
  float* cand_val = resp + (size_t)B_ * HW_;       // 16*4096 f32
  int* cand_idx = (int*)(cand_val + B_ * CAP_);    // 16*4096 i32
  float* sel_val = (float*)(cand_idx + B_ * CAP_); // 16*512 f32
  int* sel_idx = (int*)(sel_val + B_ * 512);       // 16*512 i32

  hipMemsetAsync(d_ws, 0, 256, stream);  // zero acc + counters each call
  k_resp<<<B_ * 256, 256, 0, stream>>>(imgs, resp);
  k_nms<<<B_ * 256, 256, 0, stream>>>(resp, cand_val, cand_idx, cand_cnt);
  k_topk<<<B_, 1024, 0, stream>>>(cand_val, cand_idx, cand_cnt, sel_val, sel_idx, sel_cnt);
  k_corner<<<B_, 512, 0, stream>>>(sel_val, sel_idx, sel_cnt, scores, acc);
  k_base<<<1024, 256, 0, stream>>>(scores, acc);
  k_final<<<1, 1, 0, stream>>>(acc, out);
}

// Round 2
// 207.317 us; speedup vs baseline: 3.1335x; 3.1335x over previous
//
#include <hip/hip_runtime.h>
#include <math.h>
#include <limits.h>

namespace {

constexpr int B_ = 16;
constexpr int H_ = 512;
constexpr int W_ = 512;
constexpr int HW_ = H_ * W_;
constexpr int TS_ = 32;
constexpr int CAP_ = 4096;   // one slot per 8x8 sub-block per image (64*64)
constexpr int NSEL_ = 500;

// 7-tap gaussian, sigma=1, normalized (matches reference's np.exp/sum)
__device__ __constant__ float c_gw[7] = {
    0.004433048175243746f, 0.05400558262251428f, 0.24203622937611957f,
    0.3990502796522496f,  0.24203622937611957f, 0.05400558262251428f,
    0.004433048175243746f};

__device__ inline int reflect_i(int i, int n) {
  // jnp.pad mode='reflect': -1 -> 1, n -> n-2
  return i < 0 ? -i : (i > n - 1 ? 2 * (n - 1) - i : i);
}

// K1: imgs -> GFTT response map. One block = one 32x32 output tile.
__global__ __launch_bounds__(256) void k_resp(const float* __restrict__ imgs,
                                              float* __restrict__ resp) {
  int bid = blockIdx.x;
  int bx = bid & 15, by = (bid >> 4) & 15, b = bid >> 8;
  int r0 = by * TS_, c0 = bx * TS_;
  __shared__ float g_s[40][40];
  __shared__ float p_s[3][38][38];
  __shared__ float v_s[3][TS_][38];
  int tid = threadIdx.x;
  const float* img = imgs + (size_t)b * 3 * HW_;

  // grayscale with replicate clamp (matches sobel's edge padding)
  for (int l = tid; l < 40 * 40; l += 256) {
    int lr = l / 40, lc = l % 40;
    int gr = min(max(r0 - 4 + lr, 0), H_ - 1);
    int gc = min(max(c0 - 4 + lc, 0), W_ - 1);
    int o = gr * W_ + gc;
    g_s[lr][lc] = 0.299f * img[o] + 0.587f * img[HW_ + o] + 0.114f * img[2 * HW_ + o];
  }
  __syncthreads();

  // gradient products at rows/cols tile-3 .. tile+34, reflect-mapped into image
  for (int l = tid; l < 38 * 38; l += 256) {
    int lr = l / 38, lc = l % 38;
    int ar = reflect_i(r0 - 3 + lr, H_);
    int ac = reflect_i(c0 - 3 + lc, W_);
    int rm = max(ar - 1, 0)      - (r0 - 4);
    int rz = ar                  - (r0 - 4);
    int rp = min(ar + 1, H_ - 1) - (r0 - 4);
    int cm = max(ac - 1, 0)      - (c0 - 4);
    int cz = ac                  - (c0 - 4);
    int cp = min(ac + 1, W_ - 1) - (c0 - 4);
    float gnw = g_s[rm][cm], gn = g_s[rm][cz], gne = g_s[rm][cp];
    float gw_ = g_s[rz][cm],                   ge  = g_s[rz][cp];
    float gsw = g_s[rp][cm], gs = g_s[rp][cz], gse = g_s[rp][cp];
    float dx = ((gne - gnw) + 2.f * (ge - gw_) + (gse - gsw)) * 0.125f;
    float dy = ((gsw - gnw) + 2.f * (gs - gn) + (gse - gne)) * 0.125f;
    p_s[0][lr][lc] = dx * dx;
    p_s[1][lr][lc] = dy * dy;
    p_s[2][lr][lc] = dx * dy;
  }
  __syncthreads();

  // vertical 7-tap blur
  for (int l = tid; l < TS_ * 38; l += 256) {
    int lr = l / 38, lc = l % 38;
    float s0 = 0.f, s1 = 0.f, s2 = 0.f;
#pragma unroll
    for (int k = 0; k < 7; k++) {
      float w = c_gw[k];
      s0 += w * p_s[0][lr + k][lc];
      s1 += w * p_s[1][lr + k][lc];
      s2 += w * p_s[2][lr + k][lc];
    }
    v_s[0][lr][lc] = s0;
    v_s[1][lr][lc] = s1;
    v_s[2][lr][lc] = s2;
  }
  __syncthreads();

  // horizontal blur + min-eigenvalue response
  for (int l = tid; l < TS_ * TS_; l += 256) {
    int lr = l / TS_, lc = l % TS_;
    float b0 = 0.f, b1 = 0.f, b2 = 0.f;
#pragma unroll
    for (int k = 0; k < 7; k++) {
      float w = c_gw[k];
      b0 += w * v_s[0][lr][lc + k];
      b1 += w * v_s[1][lr][lc + k];
      b2 += w * v_s[2][lr][lc + k];
    }
    float tr = b0 + b1;
    float det = b0 * b1 - b2 * b2;
    float r = 0.5f * (tr - sqrtf(fabsf(tr * tr - 4.f * det) + 1e-12f));
    resp[((size_t)b * H_ + (r0 + lr)) * W_ + (c0 + lc)] = r;
  }
}

// K2: 5x5 NMS (pad=-inf) + per-8x8-block max into DETERMINISTIC slot
// cand[b*4096 + sub_global]. No atomics. Tie-break: min flat index
// (row-major scan), matching jax.lax.top_k index-asc tie order.
__global__ __launch_bounds__(256) void k_nms(const float* __restrict__ resp,
                                             float* __restrict__ cand_val,
                                             int* __restrict__ cand_idx) {
  int bid = blockIdx.x;
  int bx = bid & 15, by = (bid >> 4) & 15, b = bid >> 8;
  int r0 = by * TS_, c0 = bx * TS_;
  __shared__ float r_s[36][36];
  __shared__ float c_s[32][32];
  int tid = threadIdx.x;
  const float* rb = resp + (size_t)b * HW_;
  for (int l = tid; l < 36 * 36; l += 256) {
    int lr = l / 36, lc = l % 36;
    int gr = r0 - 2 + lr, gc = c0 - 2 + lc;
    float v = -INFINITY;
    if (gr >= 0 && gr < H_ && gc >= 0 && gc < W_) v = rb[gr * W_ + gc];
    r_s[lr][lc] = v;
  }
  __syncthreads();
  for (int l = tid; l < 1024; l += 256) {
    int lr = l >> 5, lc = l & 31;
    float v = r_s[lr + 2][lc + 2];
    float m = -INFINITY;
#pragma unroll
    for (int u = 0; u < 5; u++)
#pragma unroll
      for (int w = 0; w < 5; w++) m = fmaxf(m, r_s[lr + u][lc + w]);
    c_s[lr][lc] = (v == m) ? v : 0.f;
  }
  __syncthreads();
  // one thread per 8x8 sub-block: max + min-index argmax, direct slot write
  if (tid < 16) {
    int sr = (tid >> 2) << 3, sc = (tid & 3) << 3;
    float m = 0.f;
    int mi = INT_MAX;
#pragma unroll
    for (int u = 0; u < 8; u++)
      for (int w = 0; w < 8; w++) {
        float v = c_s[sr + u][sc + w];
        if (v > m) { m = v; mi = (r0 + sr + u) * W_ + (c0 + sc + w); }
      }
    int subg = ((r0 + sr) >> 3) * 64 + ((c0 + sc) >> 3);
    bool pos = (m > 0.f);
    cand_val[b * CAP_ + subg] = pos ? m : -INFINITY;
    cand_idx[b * CAP_ + subg] = pos ? mi : INT_MAX;
  }
}

// K3: per-image top-500 via in-LDS bitonic sort of the fixed 4096 slots,
// order (value desc, idx asc) to match jax.lax.top_k tie-breaking.
__global__ __launch_bounds__(1024) void k_topk(const float* __restrict__ cand_val,
                                               const int* __restrict__ cand_idx,
                                               float* __restrict__ sel_val,
                                               int* __restrict__ sel_idx) {
  int b = blockIdx.x;
  __shared__ float v_s[CAP_];
  __shared__ int i_s[CAP_];
  int tid = threadIdx.x;
  for (int l = tid; l < CAP_; l += 1024) {
    v_s[l] = cand_val[b * CAP_ + l];
    i_s[l] = cand_idx[b * CAP_ + l];
  }
  __syncthreads();
  for (int k = 2; k <= CAP_; k <<= 1) {
    for (int j = k >> 1; j > 0; j >>= 1) {
      for (int t = tid; t < CAP_ / 2; t += 1024) {
        int i = ((t & ~(j - 1)) << 1) | (t & (j - 1));
        int ixj = i | j;
        bool up = ((i & k) == 0);
        float va = v_s[i], vb = v_s[ixj];
        int ia = i_s[i], ib = i_s[ixj];
        bool b_first = (vb > va) || (vb == va && ib < ia);
        bool a_first = (va > vb) || (va == vb && ia < ib);
        bool sw = up ? b_first : a_first;
        if (sw) {
          v_s[i] = vb; v_s[ixj] = va;
          i_s[i] = ib; i_s[ixj] = ia;
        }
      }
      __syncthreads();
    }
  }
  if (tid < NSEL_) {
    sel_val[b * 512 + tid] = v_s[tid];
    sel_idx[b * 512 + tid] = i_s[tid];
  }
}

// K4: second 5x5 NMS on the sparse selected set (strict-greater suppresses,
// equal survives == x==maxpool semantics) + corner BCE terms.
__global__ __launch_bounds__(512) void k_corner(const float* __restrict__ sel_val,
                                                const int* __restrict__ sel_idx,
                                                const float* __restrict__ scores,
                                                double* __restrict__ acc) {
  int b = blockIdx.x;
  __shared__ float v_s[512];
  __shared__ int h_s[512], w_s[512];
  __shared__ float wsum[8];
  int tid = threadIdx.x;
  if (tid < NSEL_) {
    v_s[tid] = sel_val[b * 512 + tid];
    int idx = sel_idx[b * 512 + tid];
    h_s[tid] = idx >> 9;
    w_s[tid] = idx & 511;
  } else {
    v_s[tid] = -INFINITY;
    h_s[tid] = -1000; w_s[tid] = -1000;
  }
  __syncthreads();
  float term = 0.f;
  if (tid < NSEL_ && v_s[tid] > 0.f) {
    float v = v_s[tid];
    int h = h_s[tid], w = w_s[tid];
    bool keep = true;
    for (int j = 0; j < NSEL_; j++) {
      if (j == tid) continue;
      int dh = h - h_s[j], dw = w - w_s[j];
      if (dh >= -2 && dh <= 2 && dw >= -2 && dw <= 2 && v_s[j] > v) {
        keep = false;
        break;
      }
    }
    if (keep) {
      float p = scores[(size_t)b * HW_ + h * W_ + w];
      float lp = fmaxf(logf(p), -100.f);
      float l1p = fmaxf(log1pf(-p), -100.f);
      term = lp - l1p;  // corner pixel swaps log1p(-p) term for log(p)
    }
  }
  for (int off = 32; off > 0; off >>= 1) term += __shfl_down(term, off);
  if ((tid & 63) == 0) wsum[tid >> 6] = term;
  __syncthreads();
  if (tid == 0) {
    double s = 0.0;
    for (int i = 0; i < 8; i++) s += (double)wsum[i];
    atomicAdd(acc, s);
  }
}

// K5: sum of clamp(log1p(-p), -100) over all pixels.
__global__ __launch_bounds__(256) void k_base(const float* __restrict__ scores,
                                              double* __restrict__ acc) {
  __shared__ float wsum[4];
  int tid = threadIdx.x;
  size_t gid = (size_t)blockIdx.x * 256 + tid;
  size_t stride = (size_t)gridDim.x * 256;
  float s = 0.f;
  const float4* s4 = (const float4*)scores;
  size_t n4 = (size_t)B_ * HW_ / 4;
  for (size_t i = gid; i < n4; i += stride) {
    float4 p = s4[i];
    s += fmaxf(log1pf(-p.x), -100.f);
    s += fmaxf(log1pf(-p.y), -100.f);
    s += fmaxf(log1pf(-p.z), -100.f);
    s += fmaxf(log1pf(-p.w), -100.f);
  }
  for (int off = 32; off > 0; off >>= 1) s += __shfl_down(s, off);
  if ((tid & 63) == 0) wsum[tid >> 6] = s;
  __syncthreads();
  if (tid == 0) {
    double t = 0.0;
    for (int i = 0; i < 4; i++) t += (double)wsum[i];
    atomicAdd(acc, t);
  }
}

__global__ void k_final(const double* __restrict__ acc, float* __restrict__ out) {
  out[0] = (float)(-acc[0] / (double)((size_t)B_ * HW_));
}

}  // namespace

extern "C" void kernel_launch(void* const* d_in, const int* in_sizes, int n_in,
                              void* d_out, int out_size, void* d_ws, size_t ws_size,
                              hipStream_t stream) {
  const float* scores = (const float*)d_in[0];
  const float* imgs = (const float*)d_in[1];
  float* out = (float*)d_out;

  char* ws = (char*)d_ws;
  double* acc = (double*)ws;                       // 8 B
  float* resp = (float*)(ws + 256);                // 16 MB
  float* cand_val = resp + (size_t)B_ * HW_;       // 16*4096 f32
  int* cand_idx = (int*)(cand_val + B_ * CAP_);    // 16*4096 i32
  float* sel_val = (float*)(cand_idx + B_ * CAP_); // 16*512 f32
  int* sel_idx = (int*)(sel_val + B_ * 512);       // 16*512 i32

  hipMemsetAsync(d_ws, 0, 256, stream);  // zero acc each call
  k_resp<<<B_ * 256, 256, 0, stream>>>(imgs, resp);
  k_nms<<<B_ * 256, 256, 0, stream>>>(resp, cand_val, cand_idx);
  k_topk<<<B_, 1024, 0, stream>>>(cand_val, cand_idx, sel_val, sel_idx);
  k_corner<<<B_, 512, 0, stream>>>(sel_val, sel_idx, scores, acc);
  k_base<<<1024, 256, 0, stream>>>(scores, acc);
  k_final<<<1, 1, 0, stream>>>(acc, out);
}

// Round 3
// 131.253 us; speedup vs baseline: 4.9494x; 1.5795x over previous
//
#include <hip/hip_runtime.h>
#include <math.h>
#include <limits.h>

namespace {

constexpr int B_ = 16;
constexpr int H_ = 512;
constexpr int W_ = 512;
constexpr int HW_ = H_ * W_;
constexpr int TS_ = 32;
constexpr int CAP_ = 4096;   // one slot per 8x8 sub-block per image (64*64)
constexpr int NSEL_ = 500;

// 7-tap gaussian, sigma=1, normalized (matches reference's np.exp/sum)
__device__ __constant__ float c_gw[7] = {
    0.004433048175243746f, 0.05400558262251428f, 0.24203622937611957f,
    0.3990502796522496f,  0.24203622937611957f, 0.05400558262251428f,
    0.004433048175243746f};

__device__ inline int reflect_i(int i, int n) {
  // jnp.pad mode='reflect': -1 -> 1, n -> n-2
  return i < 0 ? -i : (i > n - 1 ? 2 * (n - 1) - i : i);
}

// K1: imgs -> GFTT response map. One block = one 32x32 output tile.
__global__ __launch_bounds__(256) void k_resp(const float* __restrict__ imgs,
                                              float* __restrict__ resp) {
  int bid = blockIdx.x;
  int bx = bid & 15, by = (bid >> 4) & 15, b = bid >> 8;
  int r0 = by * TS_, c0 = bx * TS_;
  __shared__ float g_s[40][40];
  __shared__ float p_s[3][38][38];
  __shared__ float v_s[3][TS_][38];
  int tid = threadIdx.x;
  const float* img = imgs + (size_t)b * 3 * HW_;

  // grayscale with replicate clamp (matches sobel's edge padding)
  for (int l = tid; l < 40 * 40; l += 256) {
    int lr = l / 40, lc = l % 40;
    int gr = min(max(r0 - 4 + lr, 0), H_ - 1);
    int gc = min(max(c0 - 4 + lc, 0), W_ - 1);
    int o = gr * W_ + gc;
    g_s[lr][lc] = 0.299f * img[o] + 0.587f * img[HW_ + o] + 0.114f * img[2 * HW_ + o];
  }
  __syncthreads();

  // gradient products at rows/cols tile-3 .. tile+34, reflect-mapped into image
  for (int l = tid; l < 38 * 38; l += 256) {
    int lr = l / 38, lc = l % 38;
    int ar = reflect_i(r0 - 3 + lr, H_);
    int ac = reflect_i(c0 - 3 + lc, W_);
    int rm = max(ar - 1, 0)      - (r0 - 4);
    int rz = ar                  - (r0 - 4);
    int rp = min(ar + 1, H_ - 1) - (r0 - 4);
    int cm = max(ac - 1, 0)      - (c0 - 4);
    int cz = ac                  - (c0 - 4);
    int cp = min(ac + 1, W_ - 1) - (c0 - 4);
    float gnw = g_s[rm][cm], gn = g_s[rm][cz], gne = g_s[rm][cp];
    float gw_ = g_s[rz][cm],                   ge  = g_s[rz][cp];
    float gsw = g_s[rp][cm], gs = g_s[rp][cz], gse = g_s[rp][cp];
    float dx = ((gne - gnw) + 2.f * (ge - gw_) + (gse - gsw)) * 0.125f;
    float dy = ((gsw - gnw) + 2.f * (gs - gn) + (gse - gne)) * 0.125f;
    p_s[0][lr][lc] = dx * dx;
    p_s[1][lr][lc] = dy * dy;
    p_s[2][lr][lc] = dx * dy;
  }
  __syncthreads();

  // vertical 7-tap blur
  for (int l = tid; l < TS_ * 38; l += 256) {
    int lr = l / 38, lc = l % 38;
    float s0 = 0.f, s1 = 0.f, s2 = 0.f;
#pragma unroll
    for (int k = 0; k < 7; k++) {
      float w = c_gw[k];
      s0 += w * p_s[0][lr + k][lc];
      s1 += w * p_s[1][lr + k][lc];
      s2 += w * p_s[2][lr + k][lc];
    }
    v_s[0][lr][lc] = s0;
    v_s[1][lr][lc] = s1;
    v_s[2][lr][lc] = s2;
  }
  __syncthreads();

  // horizontal blur + min-eigenvalue response
  for (int l = tid; l < TS_ * TS_; l += 256) {
    int lr = l / TS_, lc = l % TS_;
    float b0 = 0.f, b1 = 0.f, b2 = 0.f;
#pragma unroll
    for (int k = 0; k < 7; k++) {
      float w = c_gw[k];
      b0 += w * v_s[0][lr][lc + k];
      b1 += w * v_s[1][lr][lc + k];
      b2 += w * v_s[2][lr][lc + k];
    }
    float tr = b0 + b1;
    float det = b0 * b1 - b2 * b2;
    float r = 0.5f * (tr - sqrtf(fabsf(tr * tr - 4.f * det) + 1e-12f));
    resp[((size_t)b * H_ + (r0 + lr)) * W_ + (c0 + lc)] = r;
  }
}

// K2: 5x5 NMS (pad=-inf) + per-8x8-block max into DETERMINISTIC slot
// cand[b*4096 + sub_global]. No atomics. Tie-break: min flat index
// (row-major scan), matching jax.lax.top_k index-asc tie order.
__global__ __launch_bounds__(256) void k_nms(const float* __restrict__ resp,
                                             float* __restrict__ cand_val,
                                             int* __restrict__ cand_idx) {
  int bid = blockIdx.x;
  int bx = bid & 15, by = (bid >> 4) & 15, b = bid >> 8;
  int r0 = by * TS_, c0 = bx * TS_;
  __shared__ float r_s[36][36];
  __shared__ float c_s[32][32];
  int tid = threadIdx.x;
  const float* rb = resp + (size_t)b * HW_;
  for (int l = tid; l < 36 * 36; l += 256) {
    int lr = l / 36, lc = l % 36;
    int gr = r0 - 2 + lr, gc = c0 - 2 + lc;
    float v = -INFINITY;
    if (gr >= 0 && gr < H_ && gc >= 0 && gc < W_) v = rb[gr * W_ + gc];
    r_s[lr][lc] = v;
  }
  __syncthreads();
  for (int l = tid; l < 1024; l += 256) {
    int lr = l >> 5, lc = l & 31;
    float v = r_s[lr + 2][lc + 2];
    float m = -INFINITY;
#pragma unroll
    for (int u = 0; u < 5; u++)
#pragma unroll
      for (int w = 0; w < 5; w++) m = fmaxf(m, r_s[lr + u][lc + w]);
    c_s[lr][lc] = (v == m) ? v : 0.f;
  }
  __syncthreads();
  // one thread per 8x8 sub-block: max + min-index argmax, direct slot write
  if (tid < 16) {
    int sr = (tid >> 2) << 3, sc = (tid & 3) << 3;
    float m = 0.f;
    int mi = INT_MAX;
#pragma unroll
    for (int u = 0; u < 8; u++)
      for (int w = 0; w < 8; w++) {
        float v = c_s[sr + u][sc + w];
        if (v > m) { m = v; mi = (r0 + sr + u) * W_ + (c0 + sc + w); }
      }
    int subg = ((r0 + sr) >> 3) * 64 + ((c0 + sc) >> 3);
    bool pos = (m > 0.f);
    cand_val[b * CAP_ + subg] = pos ? m : -INFINITY;
    cand_idx[b * CAP_ + subg] = pos ? mi : INT_MAX;
  }
}

// K3: per-image top-500 via in-LDS bitonic sort of the fixed 4096 slots,
// order (value desc, idx asc). FUSED tail: the second nms2d is a provable
// no-op (selected points within Chebyshev<=2 must have equal values, and
// equal survives x==maxpool), so every selected v>0 is a corner -> compute
// its BCE term swap (log p - log1p(-p)) directly and accumulate.
__global__ __launch_bounds__(1024) void k_topk(const float* __restrict__ cand_val,
                                               const int* __restrict__ cand_idx,
                                               const float* __restrict__ scores,
                                               double* __restrict__ acc) {
  int b = blockIdx.x;
  __shared__ float v_s[CAP_];
  __shared__ int i_s[CAP_];
  __shared__ float wsum[16];
  int tid = threadIdx.x;
  for (int l = tid; l < CAP_; l += 1024) {
    v_s[l] = cand_val[b * CAP_ + l];
    i_s[l] = cand_idx[b * CAP_ + l];
  }
  __syncthreads();
  for (int k = 2; k <= CAP_; k <<= 1) {
    for (int j = k >> 1; j > 0; j >>= 1) {
      for (int t = tid; t < CAP_ / 2; t += 1024) {
        int i = ((t & ~(j - 1)) << 1) | (t & (j - 1));
        int ixj = i | j;
        bool up = ((i & k) == 0);
        float va = v_s[i], vb = v_s[ixj];
        int ia = i_s[i], ib = i_s[ixj];
        bool b_first = (vb > va) || (vb == va && ib < ia);
        bool a_first = (va > vb) || (va == vb && ia < ib);
        bool sw = up ? b_first : a_first;
        if (sw) {
          v_s[i] = vb; v_s[ixj] = va;
          i_s[i] = ib; i_s[ixj] = ia;
        }
      }
      __syncthreads();
    }
  }
  // corner BCE terms for the top-500 (v>0)
  float term = 0.f;
  if (tid < NSEL_ && v_s[tid] > 0.f) {
    int idx = i_s[tid];
    float p = scores[(size_t)b * HW_ + idx];
    float lp = fmaxf(logf(p), -100.f);
    float l1p = fmaxf(log1pf(-p), -100.f);
    term = lp - l1p;  // corner pixel swaps log1p(-p) term for log(p)
  }
  for (int off = 32; off > 0; off >>= 1) term += __shfl_down(term, off);
  if ((tid & 63) == 0) wsum[tid >> 6] = term;
  __syncthreads();
  if (tid == 0) {
    double s = 0.0;
    for (int i = 0; i < 16; i++) s += (double)wsum[i];
    atomicAdd(acc, s);
  }
}

// K4: sum of clamp(log1p(-p), -100) over all pixels.
__global__ __launch_bounds__(256) void k_base(const float* __restrict__ scores,
                                              double* __restrict__ acc) {
  __shared__ float wsum[4];
  int tid = threadIdx.x;
  size_t gid = (size_t)blockIdx.x * 256 + tid;
  size_t stride = (size_t)gridDim.x * 256;
  float s = 0.f;
  const float4* s4 = (const float4*)scores;
  size_t n4 = (size_t)B_ * HW_ / 4;
  for (size_t i = gid; i < n4; i += stride) {
    float4 p = s4[i];
    s += fmaxf(log1pf(-p.x), -100.f);
    s += fmaxf(log1pf(-p.y), -100.f);
    s += fmaxf(log1pf(-p.z), -100.f);
    s += fmaxf(log1pf(-p.w), -100.f);
  }
  for (int off = 32; off > 0; off >>= 1) s += __shfl_down(s, off);
  if ((tid & 63) == 0) wsum[tid >> 6] = s;
  __syncthreads();
  if (tid == 0) {
    double t = 0.0;
    for (int i = 0; i < 4; i++) t += (double)wsum[i];
    atomicAdd(acc, t);
  }
}

__global__ void k_final(const double* __restrict__ acc, float* __restrict__ out) {
  out[0] = (float)(-acc[0] / (double)((size_t)B_ * HW_));
}

}  // namespace

extern "C" void kernel_launch(void* const* d_in, const int* in_sizes, int n_in,
                              void* d_out, int out_size, void* d_ws, size_t ws_size,
                              hipStream_t stream) {
  const float* scores = (const float*)d_in[0];
  const float* imgs = (const float*)d_in[1];
  float* out = (float*)d_out;

  char* ws = (char*)d_ws;
  double* acc = (double*)ws;                       // 8 B
  float* resp = (float*)(ws + 256);                // 16 MB
  float* cand_val = resp + (size_t)B_ * HW_;       // 16*4096 f32
  int* cand_idx = (int*)(cand_val + B_ * CAP_);    // 16*4096 i32

  hipMemsetAsync(d_ws, 0, 256, stream);  // zero acc each call
  k_resp<<<B_ * 256, 256, 0, stream>>>(imgs, resp);
  k_nms<<<B_ * 256, 256, 0, stream>>>(resp, cand_val, cand_idx);
  k_topk<<<B_, 1024, 0, stream>>>(cand_val, cand_idx, scores, acc);
  k_base<<<1024, 256, 0, stream>>>(scores, acc);
  k_final<<<1, 1, 0, stream>>>(acc, out);
}